// Round 1
// baseline (13751.126 us; speedup 1.0000x reference)
//
#include <hip/hip_runtime.h>
#include <math.h>

#define HH 512
#define WW 512
#define BB 8
#define NPIX (HH*WW)        // 262144
#define NTOT (BB*NPIX)      // 2097152
#define ITER 50

// Gaussian 5x5 (sigma=5): w1d(d) = exp(-d^2/50), d=-2..2, normalized by (sum)^2
constexpr double W0d = 0.92311634638663587;  // exp(-0.08)
constexpr double W1d = 0.98019867330675525;  // exp(-0.02)
constexpr double SUM1D = 1.0 + 2.0*(W0d + W1d);
constexpr float  INV_NORM = (float)(1.0/(SUM1D*SUM1D + 1e-15));
constexpr float  W0f = (float)W0d;
constexpr float  W1f = (float)W1d;

__device__ __forceinline__ float sigmoidf(float x) {
    return 1.0f / (1.0f + expf(-x));
}

// Block-level reduce of 6 floats (256 threads = 4 waves of 64), then atomicAdd (double)
__device__ __forceinline__ void reduce6_atomic(float v[6], double* dst) {
    #pragma unroll
    for (int k = 0; k < 6; k++) {
        float x = v[k];
        #pragma unroll
        for (int off = 32; off > 0; off >>= 1) x += __shfl_down(x, off, 64);
        v[k] = x;
    }
    __shared__ float sm[4][6];
    const int lane = threadIdx.x & 63;
    const int wv   = threadIdx.x >> 6;
    if (lane == 0) {
        #pragma unroll
        for (int k = 0; k < 6; k++) sm[wv][k] = v[k];
    }
    __syncthreads();
    if (threadIdx.x == 0) {
        #pragma unroll
        for (int k = 0; k < 6; k++) {
            float t = sm[0][k] + sm[1][k] + sm[2][k] + sm[3][k];
            atomicAdd(dst + k, (double)t);
        }
    }
}

// u0 = sigmoid(o); q0 = 0; accumulate sums[0]  (4 pixels/thread, 2048 blocks)
__global__ __launch_bounds__(256) void init_kernel(const float* __restrict__ o,
                                                   float* __restrict__ u,
                                                   float* __restrict__ q,
                                                   double* __restrict__ sums0) {
    const int t   = blockIdx.x * 256 + threadIdx.x;
    const int pix = t * 4;
    const int bb  = blockIdx.x >> 8;          // 256 blocks per batch
    const int within = pix & (NPIX - 1);
    const int i = within >> 9;
    const int j = within & (WW - 1);

    float4 ov = *(const float4*)(o + pix);
    float4 uv;
    uv.x = sigmoidf(ov.x);
    uv.y = sigmoidf(ov.y);
    uv.z = sigmoidf(ov.z);
    uv.w = sigmoidf(ov.w);
    *(float4*)(u + pix) = uv;
    *(float4*)(q + pix) = make_float4(0.f, 0.f, 0.f, 0.f);

    const float x = (float)(i + 1);
    float v[6] = {0.f, 0.f, 0.f, 0.f, 0.f, 0.f};
    float us[4] = {uv.x, uv.y, uv.z, uv.w};
    #pragma unroll
    for (int kk = 0; kk < 4; kk++) {
        float uu = us[kk];
        float y  = (float)(j + 1 + kk);
        v[0] += uu;
        v[1] += uu * x;
        v[2] += uu * y;
        v[3] += uu * x * y;
        v[4] += uu * x * x;
        v[5] += uu * y * y;
    }
    reduce6_atomic(v, sums0 + bb * 8);
}

// p = conv5x5_gauss(1 - 2u), zero-padded. block (64,4) -> tile 64x4, LDS with halo 2
__global__ __launch_bounds__(256) void conv_kernel(const float* __restrict__ u,
                                                   float* __restrict__ p) {
    const int tx = threadIdx.x;            // 0..63 -> j
    const int ty = threadIdx.y;            // 0..3  -> i
    const int j0 = blockIdx.x * 64;
    const int i0 = blockIdx.y * 4;
    const int b  = blockIdx.z;
    const float* ub = u + (size_t)b * NPIX;

    __shared__ float tile[8][68];
    const int lin = ty * 64 + tx;
    for (int e = lin; e < 8 * 68; e += 256) {
        const int r = e / 68, c = e % 68;
        const int ii = i0 - 2 + r;
        const int jj = j0 - 2 + c;
        float v = 0.f;
        if (ii >= 0 && ii < HH && jj >= 0 && jj < WW)
            v = 1.f - 2.f * ub[ii * WW + jj];
        tile[r][c] = v;
    }
    __syncthreads();

    const float w[5] = {W0f, W1f, 1.f, W1f, W0f};
    float acc = 0.f;
    #pragma unroll
    for (int a = 0; a < 5; a++) {
        float rs = 0.f;
        #pragma unroll
        for (int c = 0; c < 5; c++) rs += w[c] * tile[ty + a][tx + c];
        acc += w[a] * rs;
    }
    p[(size_t)b * NPIX + (i0 + ty) * WW + (j0 + tx)] = acc * INV_NORM;
}

// pointwise eval of (a=Tx*q_new, b=Ty*q_new, q_new) at (i,j)
__device__ __forceinline__ void eval_pt(const float* __restrict__ ub,
                                        const float* __restrict__ qb,
                                        int i, int j,
                                        float cxf, float cyf,
                                        float cossin, float bsin, float asin_,
                                        float& a, float& bv, float& qn) {
    const int off = i * WW + j;
    const float uc = ub[off];
    const float ud = (i + 1 < HH) ? ub[off + WW] : 0.f;
    const float ur = (j + 1 < WW) ? ub[off + 1] : 0.f;
    const float un0 = ud - uc;
    const float un1 = ur - uc;
    const float dx = (float)(i + 1) - cxf;
    const float dy = (float)(j + 1) - cyf;
    float Tx = -dx * cossin + dy * bsin;
    float Ty =  dy * cossin - dx * asin_;
    const float Tn = sqrtf(Tx * Tx + Ty * Ty) + 1e-10f;
    const float rn = 1.0f / Tn;
    Tx *= rn; Ty *= rn;
    qn = qb[off] - (un0 * Tx + un1 * Ty);
    a  = Tx * qn;
    bv = Ty * qn;
}

// one step: scalars from sumsIn; q_new, Tq (halo recompute), u_new=sigmoid(o-p-Tq);
// accumulate sums of u_new into sumsOut; last iter writes out = o-p-Tq
__global__ __launch_bounds__(256) void update_kernel(const float* __restrict__ o,
                                                     const float* __restrict__ uA,
                                                     const float* __restrict__ qA,
                                                     const float* __restrict__ p,
                                                     float* __restrict__ uB,
                                                     float* __restrict__ qB,
                                                     const double* __restrict__ sumsIn,
                                                     double* __restrict__ sumsOut,
                                                     float* __restrict__ out,
                                                     int lastFlag) {
    const int idx = blockIdx.x * 256 + threadIdx.x;     // NTOT threads
    const int bb  = blockIdx.x >> 10;                    // 1024 blocks per batch
    const int within = idx & (NPIX - 1);
    const int i = within >> 9;
    const int j = within & (WW - 1);

    // per-batch scalars (double for the cancellation-prone central moments)
    const double* S = sumsIn + bb * 8;
    const double s   = S[0];
    const double inv = 1.0 / s;
    const double cx  = S[1] * inv;
    const double cy  = S[2] * inv;
    const float cossin = (float)(S[3] * inv - cx * cy);
    const float bsin   = (float)(S[4] * inv - cx * cx);
    const float asin_  = (float)(S[5] * inv - cy * cy);
    const float cxf = (float)cx;
    const float cyf = (float)cy;

    const float* ub = uA + (size_t)bb * NPIX;
    const float* qb = qA + (size_t)bb * NPIX;

    float a_c, b_c, qn_c;
    eval_pt(ub, qb, i, j, cxf, cyf, cossin, bsin, asin_, a_c, b_c, qn_c);
    float Tq = a_c + b_c;
    if (i > 0) {
        float a_u, b_u, q_u;
        eval_pt(ub, qb, i - 1, j, cxf, cyf, cossin, bsin, asin_, a_u, b_u, q_u);
        Tq -= a_u;
    }
    if (j > 0) {
        float a_l, b_l, q_l;
        eval_pt(ub, qb, i, j - 1, cxf, cyf, cossin, bsin, asin_, a_l, b_l, q_l);
        Tq -= b_l;
    }

    const float t  = o[idx] - p[idx] - Tq;
    const float un = sigmoidf(t);
    uB[idx] = un;
    qB[idx] = qn_c;
    if (lastFlag) out[idx] = t;

    // sums of u_new for next iteration
    const float x = (float)(i + 1);
    const float y = (float)(j + 1);
    float v[6];
    v[0] = un;
    v[1] = un * x;
    v[2] = un * y;
    v[3] = un * x * y;
    v[4] = un * x * x;
    v[5] = un * y * y;
    reduce6_atomic(v, sumsOut + bb * 8);
}

extern "C" void kernel_launch(void* const* d_in, const int* in_sizes, int n_in,
                              void* d_out, int out_size, void* d_ws, size_t ws_size,
                              hipStream_t stream) {
    const float* o = (const float*)d_in[0];
    float* out = (float*)d_out;

    float* ws = (float*)d_ws;
    float* uA = ws;
    float* uB = ws + (size_t)NTOT;
    float* qA = ws + 2 * (size_t)NTOT;
    float* qB = ws + 3 * (size_t)NTOT;
    float* p  = ws + 4 * (size_t)NTOT;
    double* sums = (double*)(ws + 5 * (size_t)NTOT);   // 51 slots * 8 batches * 8 doubles

    hipMemsetAsync(sums, 0, 51 * 64 * sizeof(double), stream);
    init_kernel<<<2048, 256, 0, stream>>>(o, uA, qA, sums);

    float *ua = uA, *ub = uB, *qa = qA, *qb = qB;
    for (int k = 0; k < ITER; k++) {
        conv_kernel<<<dim3(8, 128, 8), dim3(64, 4), 0, stream>>>(ua, p);
        update_kernel<<<8192, 256, 0, stream>>>(o, ua, qa, p, ub, qb,
                                                sums + (size_t)k * 64,
                                                sums + (size_t)(k + 1) * 64,
                                                out, (k == ITER - 1) ? 1 : 0);
        float* tmp;
        tmp = ua; ua = ub; ub = tmp;
        tmp = qa; qa = qb; qb = tmp;
    }
}

// Round 2
// 2894.840 us; speedup vs baseline: 4.7502x; 4.7502x over previous
//
#include <hip/hip_runtime.h>
#include <math.h>

#define HH 512
#define WW 512
#define BB 8
#define NPIX (HH*WW)        // 262144
#define NTOT (BB*NPIX)      // 2097152
#define ITER 50

// sums layout: per iteration: 8 batches x 16 slots x 8 doubles (counters 0..5 used)
#define SLOTS 16
#define SLOT_STRIDE 8                 // doubles
#define BATCH_STRIDE (SLOTS*SLOT_STRIDE)   // 128 doubles
#define ITER_STRIDE (BB*BATCH_STRIDE)      // 1024 doubles

// Gaussian 5x5 (sigma=5): w1d(d) = exp(-d^2/50), d=-2..2, normalized by (sum)^2
constexpr double W0d = 0.92311634638663587;  // exp(-0.08)
constexpr double W1d = 0.98019867330675525;  // exp(-0.02)
constexpr double SUM1D = 1.0 + 2.0*(W0d + W1d);
constexpr float  INV_NORM = (float)(1.0/(SUM1D*SUM1D + 1e-15));
constexpr float  W0f = (float)W0d;
constexpr float  W1f = (float)W1d;

__device__ __forceinline__ float sigmoidf(float x) {
    return 1.0f / (1.0f + expf(-x));
}

// Block-level reduce of 6 floats (256 threads = 4 waves of 64), then atomicAdd (double)
// dst points at this block's (batch, slot) 8-double group.
__device__ __forceinline__ void reduce6_atomic(float v[6], double* dst) {
    #pragma unroll
    for (int k = 0; k < 6; k++) {
        float x = v[k];
        #pragma unroll
        for (int off = 32; off > 0; off >>= 1) x += __shfl_down(x, off, 64);
        v[k] = x;
    }
    __shared__ float sm[4][6];
    const int lane = threadIdx.x & 63;
    const int wv   = threadIdx.x >> 6;
    if (lane == 0) {
        #pragma unroll
        for (int k = 0; k < 6; k++) sm[wv][k] = v[k];
    }
    __syncthreads();
    if (threadIdx.x == 0) {
        #pragma unroll
        for (int k = 0; k < 6; k++) {
            float t = sm[0][k] + sm[1][k] + sm[2][k] + sm[3][k];
            atomicAdd(dst + k, (double)t);
        }
    }
}

// u0 = sigmoid(o); q0 = 0; accumulate sums[0]  (4 pixels/thread, 2048 blocks)
__global__ __launch_bounds__(256) void init_kernel(const float* __restrict__ o,
                                                   float* __restrict__ u,
                                                   float* __restrict__ q,
                                                   double* __restrict__ sums0) {
    const int t   = blockIdx.x * 256 + threadIdx.x;
    const int pix = t * 4;
    const int bb  = blockIdx.x >> 8;          // 256 blocks per batch
    const int within = pix & (NPIX - 1);
    const int i = within >> 9;
    const int j = within & (WW - 1);

    float4 ov = *(const float4*)(o + pix);
    float4 uv;
    uv.x = sigmoidf(ov.x);
    uv.y = sigmoidf(ov.y);
    uv.z = sigmoidf(ov.z);
    uv.w = sigmoidf(ov.w);
    *(float4*)(u + pix) = uv;
    *(float4*)(q + pix) = make_float4(0.f, 0.f, 0.f, 0.f);

    const float x = (float)(i + 1);
    float v[6] = {0.f, 0.f, 0.f, 0.f, 0.f, 0.f};
    float us[4] = {uv.x, uv.y, uv.z, uv.w};
    #pragma unroll
    for (int kk = 0; kk < 4; kk++) {
        float uu = us[kk];
        float y  = (float)(j + 1 + kk);
        v[0] += uu;
        v[1] += uu * x;
        v[2] += uu * y;
        v[3] += uu * x * y;
        v[4] += uu * x * x;
        v[5] += uu * y * y;
    }
    const int slot = blockIdx.x & (SLOTS - 1);
    reduce6_atomic(v, sums0 + bb * BATCH_STRIDE + slot * SLOT_STRIDE);
}

// p = conv5x5_gauss(1 - 2u), zero-padded. block (64,4) -> tile 64x4, LDS with halo 2
__global__ __launch_bounds__(256) void conv_kernel(const float* __restrict__ u,
                                                   float* __restrict__ p) {
    const int tx = threadIdx.x;            // 0..63 -> j
    const int ty = threadIdx.y;            // 0..3  -> i
    const int j0 = blockIdx.x * 64;
    const int i0 = blockIdx.y * 4;
    const int b  = blockIdx.z;
    const float* ub = u + (size_t)b * NPIX;

    __shared__ float tile[8][68];
    const int lin = ty * 64 + tx;
    for (int e = lin; e < 8 * 68; e += 256) {
        const int r = e / 68, c = e % 68;
        const int ii = i0 - 2 + r;
        const int jj = j0 - 2 + c;
        float v = 0.f;
        if (ii >= 0 && ii < HH && jj >= 0 && jj < WW)
            v = 1.f - 2.f * ub[ii * WW + jj];
        tile[r][c] = v;
    }
    __syncthreads();

    const float w[5] = {W0f, W1f, 1.f, W1f, W0f};
    float acc = 0.f;
    #pragma unroll
    for (int a = 0; a < 5; a++) {
        float rs = 0.f;
        #pragma unroll
        for (int c = 0; c < 5; c++) rs += w[c] * tile[ty + a][tx + c];
        acc += w[a] * rs;
    }
    p[(size_t)b * NPIX + (i0 + ty) * WW + (j0 + tx)] = acc * INV_NORM;
}

// pointwise eval of (a=Tx*q_new, b=Ty*q_new, q_new) at (i,j)
__device__ __forceinline__ void eval_pt(const float* __restrict__ ub,
                                        const float* __restrict__ qb,
                                        int i, int j,
                                        float cxf, float cyf,
                                        float cossin, float bsin, float asin_,
                                        float& a, float& bv, float& qn) {
    const int off = i * WW + j;
    const float uc = ub[off];
    const float ud = (i + 1 < HH) ? ub[off + WW] : 0.f;
    const float ur = (j + 1 < WW) ? ub[off + 1] : 0.f;
    const float un0 = ud - uc;
    const float un1 = ur - uc;
    const float dx = (float)(i + 1) - cxf;
    const float dy = (float)(j + 1) - cyf;
    float Tx = -dx * cossin + dy * bsin;
    float Ty =  dy * cossin - dx * asin_;
    const float Tn = sqrtf(Tx * Tx + Ty * Ty) + 1e-10f;
    const float rn = 1.0f / Tn;
    Tx *= rn; Ty *= rn;
    qn = qb[off] - (un0 * Tx + un1 * Ty);
    a  = Tx * qn;
    bv = Ty * qn;
}

// one step: finalize per-batch scalars from 16 spread slots (once per block),
// q_new, Tq (halo recompute), u_new=sigmoid(o-p-Tq);
// accumulate sums of u_new into sumsOut (spread); last iter writes out = o-p-Tq
__global__ __launch_bounds__(256) void update_kernel(const float* __restrict__ o,
                                                     const float* __restrict__ uA,
                                                     const float* __restrict__ qA,
                                                     const float* __restrict__ p,
                                                     float* __restrict__ uB,
                                                     float* __restrict__ qB,
                                                     const double* __restrict__ sumsIn,
                                                     double* __restrict__ sumsOut,
                                                     float* __restrict__ out,
                                                     int lastFlag) {
    const int idx = blockIdx.x * 256 + threadIdx.x;     // NTOT threads
    const int bb  = blockIdx.x >> 10;                    // 1024 blocks per batch
    const int within = idx & (NPIX - 1);
    const int i = within >> 9;
    const int j = within & (WW - 1);

    // finalize per-batch scalars once per block: lanes 0..15 each read one slot
    __shared__ float sc[5];   // cx, cy, cossin, bsin, asin
    if (threadIdx.x < 16) {
        const double* S = sumsIn + bb * BATCH_STRIDE + threadIdx.x * SLOT_STRIDE;
        double v[6];
        #pragma unroll
        for (int c = 0; c < 6; c++) v[c] = S[c];
        #pragma unroll
        for (int off = 8; off > 0; off >>= 1) {
            #pragma unroll
            for (int c = 0; c < 6; c++) v[c] += __shfl_down(v[c], off, 64);
        }
        if (threadIdx.x == 0) {
            const double s   = v[0];
            const double inv = 1.0 / s;
            const double cx  = v[1] * inv;
            const double cy  = v[2] * inv;
            sc[0] = (float)cx;
            sc[1] = (float)cy;
            sc[2] = (float)(v[3] * inv - cx * cy);
            sc[3] = (float)(v[4] * inv - cx * cx);
            sc[4] = (float)(v[5] * inv - cy * cy);
        }
    }
    __syncthreads();
    const float cxf    = sc[0];
    const float cyf    = sc[1];
    const float cossin = sc[2];
    const float bsin   = sc[3];
    const float asin_  = sc[4];

    const float* ub = uA + (size_t)bb * NPIX;
    const float* qb = qA + (size_t)bb * NPIX;

    float a_c, b_c, qn_c;
    eval_pt(ub, qb, i, j, cxf, cyf, cossin, bsin, asin_, a_c, b_c, qn_c);
    float Tq = a_c + b_c;
    if (i > 0) {
        float a_u, b_u, q_u;
        eval_pt(ub, qb, i - 1, j, cxf, cyf, cossin, bsin, asin_, a_u, b_u, q_u);
        Tq -= a_u;
    }
    if (j > 0) {
        float a_l, b_l, q_l;
        eval_pt(ub, qb, i, j - 1, cxf, cyf, cossin, bsin, asin_, a_l, b_l, q_l);
        Tq -= b_l;
    }

    const float t  = o[idx] - p[idx] - Tq;
    const float un = sigmoidf(t);
    uB[idx] = un;
    qB[idx] = qn_c;
    if (lastFlag) out[idx] = t;

    // sums of u_new for next iteration (spread across 16 slots per batch)
    const float x = (float)(i + 1);
    const float y = (float)(j + 1);
    float v[6];
    v[0] = un;
    v[1] = un * x;
    v[2] = un * y;
    v[3] = un * x * y;
    v[4] = un * x * x;
    v[5] = un * y * y;
    const int slot = blockIdx.x & (SLOTS - 1);
    reduce6_atomic(v, sumsOut + bb * BATCH_STRIDE + slot * SLOT_STRIDE);
}

extern "C" void kernel_launch(void* const* d_in, const int* in_sizes, int n_in,
                              void* d_out, int out_size, void* d_ws, size_t ws_size,
                              hipStream_t stream) {
    const float* o = (const float*)d_in[0];
    float* out = (float*)d_out;

    float* ws = (float*)d_ws;
    float* uA = ws;
    float* uB = ws + (size_t)NTOT;
    float* qA = ws + 2 * (size_t)NTOT;
    float* qB = ws + 3 * (size_t)NTOT;
    float* p  = ws + 4 * (size_t)NTOT;
    double* sums = (double*)(ws + 5 * (size_t)NTOT);   // 51 iters * 1024 doubles

    hipMemsetAsync(sums, 0, (size_t)(ITER + 1) * ITER_STRIDE * sizeof(double), stream);
    init_kernel<<<2048, 256, 0, stream>>>(o, uA, qA, sums);

    float *ua = uA, *ub = uB, *qa = qA, *qb = qB;
    for (int k = 0; k < ITER; k++) {
        conv_kernel<<<dim3(8, 128, 8), dim3(64, 4), 0, stream>>>(ua, p);
        update_kernel<<<8192, 256, 0, stream>>>(o, ua, qa, p, ub, qb,
                                                sums + (size_t)k * ITER_STRIDE,
                                                sums + (size_t)(k + 1) * ITER_STRIDE,
                                                out, (k == ITER - 1) ? 1 : 0);
        float* tmp;
        tmp = ua; ua = ub; ub = tmp;
        tmp = qa; qa = qb; qb = tmp;
    }
}

// Round 3
// 1094.493 us; speedup vs baseline: 12.5639x; 2.6449x over previous
//
#include <hip/hip_runtime.h>
#include <math.h>

#define HH 512
#define WW 512
#define BB 8
#define NPIX (HH*WW)        // 262144
#define NTOT (BB*NPIX)      // 2097152
#define ITER 50

#define TX 64
#define TY 16

// sums layout: per iteration: 8 batches x 16 slots x 8 doubles (counters 0..5 used)
#define SLOTS 16
#define SLOT_STRIDE 8                      // doubles
#define BATCH_STRIDE (SLOTS*SLOT_STRIDE)   // 128 doubles
#define ITER_STRIDE (BB*BATCH_STRIDE)      // 1024 doubles

// Gaussian 5x5 (sigma=5): w1d(d) = exp(-d^2/50), d=-2..2, normalized by (sum)^2
constexpr double W0d = 0.92311634638663587;  // exp(-0.08)
constexpr double W1d = 0.98019867330675525;  // exp(-0.02)
constexpr double SUM1D = 1.0 + 2.0*(W0d + W1d);
constexpr float  INV_NORM = (float)(1.0/(SUM1D*SUM1D + 1e-15));
constexpr float  W0f = (float)W0d;
constexpr float  W1f = (float)W1d;
constexpr float  S1f = (float)SUM1D;

__device__ __forceinline__ float sigmoidf(float x) {
    return 1.0f / (1.0f + expf(-x));
}

// in-bounds 1D weight sum at coordinate v (0..511); image is 512 in both dims
__device__ __forceinline__ float edge1d(int v) {
    float r = S1f;
    if (v == 0 || v == HH - 1) r = S1f - W0f - W1f;
    else if (v == 1 || v == HH - 2) r = S1f - W0f;
    return r;
}

// Block-level reduce of 6 floats (256 threads = 4 waves), then atomicAdd (double)
__device__ __forceinline__ void reduce6_atomic(float v[6], double* dst) {
    #pragma unroll
    for (int k = 0; k < 6; k++) {
        float x = v[k];
        #pragma unroll
        for (int off = 32; off > 0; off >>= 1) x += __shfl_down(x, off, 64);
        v[k] = x;
    }
    __shared__ float sm[4][6];
    const int lane = threadIdx.x & 63;
    const int wv   = threadIdx.x >> 6;
    if (lane == 0) {
        #pragma unroll
        for (int k = 0; k < 6; k++) sm[wv][k] = v[k];
    }
    __syncthreads();
    if (threadIdx.x == 0) {
        #pragma unroll
        for (int k = 0; k < 6; k++) {
            float t = sm[0][k] + sm[1][k] + sm[2][k] + sm[3][k];
            atomicAdd(dst + k, (double)t);
        }
    }
}

// orientation-field pointwise eval; u values passed in (from LDS), q from global
__device__ __forceinline__ void evalF(float uc, float ud, float ur, float qv,
                                      float dx, float dy,
                                      float cossin, float bsin, float asin_,
                                      float& a, float& bv, float& qn) {
    float Tx = -dx * cossin + dy * bsin;
    float Ty =  dy * cossin - dx * asin_;
    const float rn = 1.0f / (sqrtf(Tx * Tx + Ty * Ty) + 1e-10f);
    Tx *= rn; Ty *= rn;
    qn = qv - ((ud - uc) * Tx + (ur - uc) * Ty);
    a  = Tx * qn;
    bv = Ty * qn;
}

// u0 = sigmoid(o); q0 = 0; accumulate sums[0]  (4 pixels/thread, 2048 blocks)
__global__ __launch_bounds__(256) void init_kernel(const float* __restrict__ o,
                                                   float* __restrict__ u,
                                                   float* __restrict__ q,
                                                   double* __restrict__ sums0) {
    const int t   = blockIdx.x * 256 + threadIdx.x;
    const int pix = t * 4;
    const int bb  = blockIdx.x >> 8;          // 256 blocks per batch
    const int within = pix & (NPIX - 1);
    const int i = within >> 9;
    const int j = within & (WW - 1);

    float4 ov = *(const float4*)(o + pix);
    float4 uv;
    uv.x = sigmoidf(ov.x);
    uv.y = sigmoidf(ov.y);
    uv.z = sigmoidf(ov.z);
    uv.w = sigmoidf(ov.w);
    *(float4*)(u + pix) = uv;
    *(float4*)(q + pix) = make_float4(0.f, 0.f, 0.f, 0.f);

    const float x = (float)(i + 1);
    float v[6] = {0.f, 0.f, 0.f, 0.f, 0.f, 0.f};
    float us[4] = {uv.x, uv.y, uv.z, uv.w};
    #pragma unroll
    for (int kk = 0; kk < 4; kk++) {
        float uu = us[kk];
        float y  = (float)(j + 1 + kk);
        v[0] += uu;
        v[1] += uu * x;
        v[2] += uu * y;
        v[3] += uu * x * y;
        v[4] += uu * x * x;
        v[5] += uu * y * y;
    }
    const int slot = blockIdx.x & (SLOTS - 1);
    reduce6_atomic(v, sums0 + bb * BATCH_STRIDE + slot * SLOT_STRIDE);
}

// One fused iteration: scalars finalize + 5x5 gaussian (separable, LDS) +
// q update + Tq divergence (halo reuse/recompute) + u_new + next-iter sums.
__global__ __launch_bounds__(256) void step_kernel(const float* __restrict__ o,
                                                   const float* __restrict__ uA,
                                                   const float* __restrict__ qA,
                                                   float* __restrict__ uB,
                                                   float* __restrict__ qB,
                                                   const double* __restrict__ sumsIn,
                                                   double* __restrict__ sumsOut,
                                                   float* __restrict__ out,
                                                   int lastFlag) {
    const int j0 = blockIdx.x * TX;
    const int i0 = blockIdx.y * TY;
    const int b  = blockIdx.z;
    const float* ubase = uA + (size_t)b * NPIX;
    const float* qbase = qA + (size_t)b * NPIX;

    __shared__ float su[TY + 4][TX + 4];   // u tile, rows i0-2..i0+TY+1, cols j0-2..j0+TX+1, 0 OOB
    __shared__ float sh[TY + 4][TX];       // horizontally gaussian-filtered u (unnormalized)
    __shared__ float sc[5];                // cx, cy, cossin, bsin, asin

    const int lin = threadIdx.x;

    // per-batch scalar finalize: lanes 0..15 read the 16 spread slots
    if (lin < 16) {
        const double* S = sumsIn + b * BATCH_STRIDE + lin * SLOT_STRIDE;
        double v[6];
        #pragma unroll
        for (int c = 0; c < 6; c++) v[c] = S[c];
        #pragma unroll
        for (int off = 8; off > 0; off >>= 1) {
            #pragma unroll
            for (int c = 0; c < 6; c++) v[c] += __shfl_down(v[c], off, 64);
        }
        if (lin == 0) {
            const double s   = v[0];
            const double inv = 1.0 / s;
            const double cx  = v[1] * inv;
            const double cy  = v[2] * inv;
            sc[0] = (float)cx;
            sc[1] = (float)cy;
            sc[2] = (float)(v[3] * inv - cx * cy);
            sc[3] = (float)(v[4] * inv - cx * cx);
            sc[4] = (float)(v[5] * inv - cy * cy);
        }
    }

    // stage u tile (zeros OOB — matches both conv's 1-2u trick and eval's padding)
    #pragma unroll
    for (int e = lin; e < (TY + 4) * (TX + 4); e += 256) {
        const int r = e / (TX + 4), c = e % (TX + 4);
        const int ii = i0 - 2 + r;
        const int jj = j0 - 2 + c;
        float v = 0.f;
        if (ii >= 0 && ii < HH && jj >= 0 && jj < WW) v = ubase[ii * WW + jj];
        su[r][c] = v;
    }
    __syncthreads();

    // horizontal gaussian pass (unnormalized weights)
    #pragma unroll
    for (int e = lin; e < (TY + 4) * TX; e += 256) {
        const int r = e >> 6, c = e & 63;
        sh[r][c] = W0f * su[r][c] + W1f * su[r][c + 1] + su[r][c + 2]
                 + W1f * su[r][c + 3] + W0f * su[r][c + 4];
    }
    __syncthreads();

    const float cxf    = sc[0];
    const float cyf    = sc[1];
    const float cossin = sc[2];
    const float bsin   = sc[3];
    const float asin_  = sc[4];

    const int tx = lin & 15;          // 16 groups of 4 pixels in x
    const int ty = lin >> 4;          // 16 rows
    const int i  = i0 + ty;
    const int jb = j0 + tx * 4;
    const int loff = i * WW + jb;
    const size_t goff = (size_t)b * NPIX + loff;

    // vertical gaussian pass + analytic zero-pad correction: p = INV_NORM*(R(i)C(j) - 2*convU)
    const float Ri = edge1d(i);
    float p4[4];
    #pragma unroll
    for (int k = 0; k < 4; k++) {
        const int c = tx * 4 + k;
        const float convU = W0f * sh[ty][c] + W1f * sh[ty + 1][c] + sh[ty + 2][c]
                          + W1f * sh[ty + 3][c] + W0f * sh[ty + 4][c];
        p4[k] = INV_NORM * (Ri * edge1d(jb + k) - 2.0f * convU);
    }

    // q loads (vectorized)
    const float4 qc4 = *(const float4*)(qbase + loff);
    float4 qu4 = make_float4(0.f, 0.f, 0.f, 0.f);
    if (i > 0) qu4 = *(const float4*)(qbase + loff - WW);
    float qlv = 0.f;
    if (jb > 0) qlv = qbase[loff - 1];
    const float4 o4 = *(const float4*)(o + goff);

    const float dx  = (float)(i + 1) - cxf;
    const float dxu = (float)i - cxf;

    const float qcv[4] = {qc4.x, qc4.y, qc4.z, qc4.w};
    const float quv[4] = {qu4.x, qu4.y, qu4.z, qu4.w};
    const float ov4[4] = {o4.x, o4.y, o4.z, o4.w};

    float a_c[4], b_c[4], qn[4], a_u[4];
    #pragma unroll
    for (int k = 0; k < 4; k++) {
        const int c = tx * 4 + 2 + k;
        const float dy = (float)(jb + k + 1) - cyf;
        evalF(su[ty + 2][c], su[ty + 3][c], su[ty + 2][c + 1], qcv[k],
              dx, dy, cossin, bsin, asin_, a_c[k], b_c[k], qn[k]);
        if (i > 0) {
            float bu_dummy, qu_dummy;
            evalF(su[ty + 1][c], su[ty + 2][c], su[ty + 1][c + 1], quv[k],
                  dxu, dy, cossin, bsin, asin_, a_u[k], bu_dummy, qu_dummy);
        } else {
            a_u[k] = 0.f;
        }
    }
    // left-neighbor b for element 0 (elements 1..3 reuse b_c[k-1])
    float b_l = 0.f;
    if (jb > 0) {
        const int c = tx * 4 + 1;
        float al_d, ql_d;
        evalF(su[ty + 2][c], su[ty + 3][c], su[ty + 2][c + 1], qlv,
              dx, (float)jb - cyf, cossin, bsin, asin_, al_d, b_l, ql_d);
    }

    float un4[4], t4[4];
    #pragma unroll
    for (int k = 0; k < 4; k++) {
        const float bleft = (k == 0) ? b_l : b_c[k - 1];
        const float Tq = a_c[k] + b_c[k] - a_u[k] - bleft;
        t4[k]  = ov4[k] - p4[k] - Tq;
        un4[k] = sigmoidf(t4[k]);
    }

    *(float4*)(uB + goff) = make_float4(un4[0], un4[1], un4[2], un4[3]);
    *(float4*)(qB + goff) = make_float4(qn[0], qn[1], qn[2], qn[3]);
    if (lastFlag) *(float4*)((float*)out + goff) = make_float4(t4[0], t4[1], t4[2], t4[3]);

    // next-iteration sums: exploit x = const per thread
    const float x = (float)(i + 1);
    float s0 = 0.f, sy = 0.f, syy = 0.f;
    #pragma unroll
    for (int k = 0; k < 4; k++) {
        const float y = (float)(jb + k + 1);
        s0  += un4[k];
        sy  += un4[k] * y;
        syy += un4[k] * y * y;
    }
    float v[6] = {s0, x * s0, sy, x * sy, x * x * s0, syy};
    const int slot = (blockIdx.y * 8 + blockIdx.x) & (SLOTS - 1);
    reduce6_atomic(v, sumsOut + b * BATCH_STRIDE + slot * SLOT_STRIDE);
}

extern "C" void kernel_launch(void* const* d_in, const int* in_sizes, int n_in,
                              void* d_out, int out_size, void* d_ws, size_t ws_size,
                              hipStream_t stream) {
    const float* o = (const float*)d_in[0];
    float* out = (float*)d_out;

    float* ws = (float*)d_ws;
    float* uA = ws;
    float* uB = ws + (size_t)NTOT;
    float* qA = ws + 2 * (size_t)NTOT;
    float* qB = ws + 3 * (size_t)NTOT;
    double* sums = (double*)(ws + 4 * (size_t)NTOT);   // 51 iters * 1024 doubles

    hipMemsetAsync(sums, 0, (size_t)(ITER + 1) * ITER_STRIDE * sizeof(double), stream);
    init_kernel<<<2048, 256, 0, stream>>>(o, uA, qA, sums);

    float *ua = uA, *ub = uB, *qa = qA, *qb = qB;
    for (int k = 0; k < ITER; k++) {
        step_kernel<<<dim3(WW / TX, HH / TY, BB), 256, 0, stream>>>(
            o, ua, qa, ub, qb,
            sums + (size_t)k * ITER_STRIDE,
            sums + (size_t)(k + 1) * ITER_STRIDE,
            out, (k == ITER - 1) ? 1 : 0);
        float* tmp;
        tmp = ua; ua = ub; ub = tmp;
        tmp = qa; qa = qb; qb = tmp;
    }
}

// Round 4
// 992.715 us; speedup vs baseline: 13.8520x; 1.1025x over previous
//
#include <hip/hip_runtime.h>
#include <math.h>

#define HH 512
#define WW 512
#define BB 8
#define NPIX (HH*WW)        // 262144
#define NTOT (BB*NPIX)      // 2097152
#define ITER 50

#define TX 64
#define TY 16
#define SU_STRIDE 72        // floats; 288 B rows -> 16B aligned, quad-uniform for b128
#define SH_STRIDE 64        // floats; 256 B rows

// sums layout: per iteration: 8 batches x 16 slots x 8 doubles (counters 0..5 used)
#define SLOTS 16
#define SLOT_STRIDE 8                      // doubles
#define BATCH_STRIDE (SLOTS*SLOT_STRIDE)   // 128 doubles
#define ITER_STRIDE (BB*BATCH_STRIDE)      // 1024 doubles

// Gaussian 5x5 (sigma=5): w1d(d) = exp(-d^2/50), d=-2..2, normalized by (sum)^2
constexpr double W0d = 0.92311634638663587;  // exp(-0.08)
constexpr double W1d = 0.98019867330675525;  // exp(-0.02)
constexpr double SUM1D = 1.0 + 2.0*(W0d + W1d);
constexpr float  INV_NORM = (float)(1.0/(SUM1D*SUM1D + 1e-15));
constexpr float  W0f = (float)W0d;
constexpr float  W1f = (float)W1d;
constexpr float  S1f = (float)SUM1D;

__device__ __forceinline__ float sigmoidf(float x) {
    return 1.0f / (1.0f + expf(-x));
}

// in-bounds 1D weight sum at coordinate v (0..511)
__device__ __forceinline__ float edge1d(int v) {
    float r = S1f;
    if (v == 0 || v == HH - 1) r = S1f - W0f - W1f;
    else if (v == 1 || v == HH - 2) r = S1f - W0f;
    return r;
}

// Block-level reduce of 6 floats (256 threads = 4 waves), then atomicAdd (double)
__device__ __forceinline__ void reduce6_atomic(float v[6], double* dst) {
    #pragma unroll
    for (int k = 0; k < 6; k++) {
        float x = v[k];
        #pragma unroll
        for (int off = 32; off > 0; off >>= 1) x += __shfl_down(x, off, 64);
        v[k] = x;
    }
    __shared__ float sm[4][6];
    const int lane = threadIdx.x & 63;
    const int wv   = threadIdx.x >> 6;
    if (lane == 0) {
        #pragma unroll
        for (int k = 0; k < 6; k++) sm[wv][k] = v[k];
    }
    __syncthreads();
    if (threadIdx.x == 0) {
        #pragma unroll
        for (int k = 0; k < 6; k++) {
            float t = sm[0][k] + sm[1][k] + sm[2][k] + sm[3][k];
            atomicAdd(dst + k, (double)t);
        }
    }
}

// orientation-field pointwise eval
__device__ __forceinline__ void evalF(float uc, float ud, float ur, float qv,
                                      float dx, float dy,
                                      float cossin, float bsin, float asin_,
                                      float& a, float& bv, float& qn) {
    float Tx = -dx * cossin + dy * bsin;
    float Ty =  dy * cossin - dx * asin_;
    const float rn = 1.0f / (sqrtf(Tx * Tx + Ty * Ty) + 1e-10f);
    Tx *= rn; Ty *= rn;
    qn = qv - ((ud - uc) * Tx + (ur - uc) * Ty);
    a  = Tx * qn;
    bv = Ty * qn;
}

// u0 = sigmoid(o); q0 = 0; accumulate sums[0]  (4 pixels/thread, 2048 blocks)
__global__ __launch_bounds__(256) void init_kernel(const float* __restrict__ o,
                                                   float* __restrict__ u,
                                                   float* __restrict__ q,
                                                   double* __restrict__ sums0) {
    const int t   = blockIdx.x * 256 + threadIdx.x;
    const int pix = t * 4;
    const int bb  = blockIdx.x >> 8;          // 256 blocks per batch
    const int within = pix & (NPIX - 1);
    const int i = within >> 9;
    const int j = within & (WW - 1);

    float4 ov = *(const float4*)(o + pix);
    float4 uv;
    uv.x = sigmoidf(ov.x);
    uv.y = sigmoidf(ov.y);
    uv.z = sigmoidf(ov.z);
    uv.w = sigmoidf(ov.w);
    *(float4*)(u + pix) = uv;
    *(float4*)(q + pix) = make_float4(0.f, 0.f, 0.f, 0.f);

    const float x = (float)(i + 1);
    float v[6] = {0.f, 0.f, 0.f, 0.f, 0.f, 0.f};
    float us[4] = {uv.x, uv.y, uv.z, uv.w};
    #pragma unroll
    for (int kk = 0; kk < 4; kk++) {
        float uu = us[kk];
        float y  = (float)(j + 1 + kk);
        v[0] += uu;
        v[1] += uu * x;
        v[2] += uu * y;
        v[3] += uu * x * y;
        v[4] += uu * x * x;
        v[5] += uu * y * y;
    }
    const int slot = blockIdx.x & (SLOTS - 1);
    reduce6_atomic(v, sums0 + bb * BATCH_STRIDE + slot * SLOT_STRIDE);
}

// One fused iteration, all-vectorized LDS.
// su tile col t <-> image col j0 + t - 4 (t=2..69 valid; rows: r <-> i0 + r - 2)
__global__ __launch_bounds__(256) void step_kernel(const float* __restrict__ o,
                                                   const float* __restrict__ uA,
                                                   const float* __restrict__ qA,
                                                   float* __restrict__ uB,
                                                   float* __restrict__ qB,
                                                   const double* __restrict__ sumsIn,
                                                   double* __restrict__ sumsOut,
                                                   float* __restrict__ out,
                                                   int lastFlag) {
    const int j0 = blockIdx.x * TX;
    const int i0 = blockIdx.y * TY;
    const int b  = blockIdx.z;
    const float* ubase = uA + (size_t)b * NPIX;
    const float* qbase = qA + (size_t)b * NPIX;

    __shared__ __align__(16) float su[TY + 4][SU_STRIDE];
    __shared__ __align__(16) float sh[TY + 4][SH_STRIDE];
    __shared__ float sc[5];                // cx, cy, cossin, bsin, asin

    const int lin = threadIdx.x;

    // per-batch scalar finalize (wave 0, lanes 0..15), overlapped with staging
    if (lin < 16) {
        const double* S = sumsIn + b * BATCH_STRIDE + lin * SLOT_STRIDE;
        double v[6];
        #pragma unroll
        for (int c = 0; c < 6; c++) v[c] = S[c];
        #pragma unroll
        for (int off = 8; off > 0; off >>= 1) {
            #pragma unroll
            for (int c = 0; c < 6; c++) v[c] += __shfl_down(v[c], off, 64);
        }
        if (lin == 0) {
            const double s   = v[0];
            const double inv = 1.0 / s;
            const double cx  = v[1] * inv;
            const double cy  = v[2] * inv;
            sc[0] = (float)cx;
            sc[1] = (float)cy;
            sc[2] = (float)(v[3] * inv - cx * cy);
            sc[3] = (float)(v[4] * inv - cx * cx);
            sc[4] = (float)(v[5] * inv - cy * cy);
        }
    }

    // ---- stage u tile: main body as float4 (20 rows x 16 groups) ----
    #pragma unroll
    for (int e = lin; e < (TY + 4) * 16; e += 256) {
        const int r = e >> 4, g = e & 15;
        const int ii = i0 + r - 2;
        float4 v = make_float4(0.f, 0.f, 0.f, 0.f);
        if (ii >= 0 && ii < HH)
            v = *(const float4*)(ubase + ii * WW + j0 + 4 * g);
        *(float4*)&su[r][4 * g + 4] = v;
    }
    // halo columns: t=2,3 (img j0-2,j0-1) and t=68,69 (img j0+64,j0+65); zero OOB
    if (lin < TY + 4) {
        const int r = lin;
        const int ii = i0 + r - 2;
        float2 lv = make_float2(0.f, 0.f);
        float2 rv = make_float2(0.f, 0.f);
        if (ii >= 0 && ii < HH) {
            if (j0 > 0)       lv = *(const float2*)(ubase + ii * WW + j0 - 2);
            if (j0 + TX < WW) rv = *(const float2*)(ubase + ii * WW + j0 + TX);
        }
        *(float2*)&su[r][2]  = lv;
        *(float2*)&su[r][68] = rv;
    }
    __syncthreads();

    // ---- horizontal gaussian pass: 4 outputs per task from 3 float4 reads ----
    // sh[r][c] = sum_d w[d] * u(img col j0+c-2+d) = window over su t = c+2..c+6
    #pragma unroll
    for (int e = lin; e < (TY + 4) * 16; e += 256) {
        const int r = e >> 4, g = e & 15;
        const int c0 = 4 * g;
        const float4 A  = *(const float4*)&su[r][c0];
        const float4 Bv = *(const float4*)&su[r][c0 + 4];
        const float4 Cv = *(const float4*)&su[r][c0 + 8];
        const float v0 = A.z,  v1 = A.w,  v2 = Bv.x, v3 = Bv.y;
        const float v4 = Bv.z, v5 = Bv.w, v6 = Cv.x, v7 = Cv.y;
        float4 hres;
        hres.x = W0f * v0 + W1f * v1 + v2 + W1f * v3 + W0f * v4;
        hres.y = W0f * v1 + W1f * v2 + v3 + W1f * v4 + W0f * v5;
        hres.z = W0f * v2 + W1f * v3 + v4 + W1f * v5 + W0f * v6;
        hres.w = W0f * v3 + W1f * v4 + v5 + W1f * v6 + W0f * v7;
        *(float4*)&sh[r][c0] = hres;
    }
    __syncthreads();

    const float cxf    = sc[0];
    const float cyf    = sc[1];
    const float cossin = sc[2];
    const float bsin   = sc[3];
    const float asin_  = sc[4];

    const int tx = lin & 15;
    const int ty = lin >> 4;
    const int i  = i0 + ty;
    const int jb = j0 + 4 * tx;
    const int loff = i * WW + jb;
    const size_t goff = (size_t)b * NPIX + loff;

    // ---- vertical gaussian pass (5 float4 reads) + analytic zero-pad fix ----
    float p4[4];
    {
        const float4 r0 = *(const float4*)&sh[ty][4 * tx];
        const float4 r1 = *(const float4*)&sh[ty + 1][4 * tx];
        const float4 r2 = *(const float4*)&sh[ty + 2][4 * tx];
        const float4 r3 = *(const float4*)&sh[ty + 3][4 * tx];
        const float4 r4 = *(const float4*)&sh[ty + 4][4 * tx];
        const float cU0 = W0f * r0.x + W1f * r1.x + r2.x + W1f * r3.x + W0f * r4.x;
        const float cU1 = W0f * r0.y + W1f * r1.y + r2.y + W1f * r3.y + W0f * r4.y;
        const float cU2 = W0f * r0.z + W1f * r1.z + r2.z + W1f * r3.z + W0f * r4.z;
        const float cU3 = W0f * r0.w + W1f * r1.w + r2.w + W1f * r3.w + W0f * r4.w;
        const float Ri = edge1d(i);
        p4[0] = INV_NORM * (Ri * edge1d(jb)     - 2.0f * cU0);
        p4[1] = INV_NORM * (Ri * edge1d(jb + 1) - 2.0f * cU1);
        p4[2] = INV_NORM * (Ri * edge1d(jb + 2) - 2.0f * cU2);
        p4[3] = INV_NORM * (Ri * edge1d(jb + 3) - 2.0f * cU3);
    }

    // ---- u fragments (all aligned float4; quad-uniform -> conflict-free) ----
    const float4 u1a = *(const float4*)&su[ty + 1][4 * tx + 4];
    const float4 u1b = *(const float4*)&su[ty + 1][4 * tx + 8];
    const float4 u2z = *(const float4*)&su[ty + 2][4 * tx];
    const float4 u2a = *(const float4*)&su[ty + 2][4 * tx + 4];
    const float4 u2b = *(const float4*)&su[ty + 2][4 * tx + 8];
    const float4 u3z = *(const float4*)&su[ty + 3][4 * tx];
    const float4 u3a = *(const float4*)&su[ty + 3][4 * tx + 4];

    const float uc[5] = {u2a.x, u2a.y, u2a.z, u2a.w, u2b.x};   // row i,   t=4tx+4..8
    const float ud[4] = {u3a.x, u3a.y, u3a.z, u3a.w};          // row i+1
    const float uu[5] = {u1a.x, u1a.y, u1a.z, u1a.w, u1b.x};   // row i-1

    // ---- q / o loads (clamped addresses, branchless select) ----
    const float4 qc4 = *(const float4*)(qbase + loff);
    const float4 qu4 = *(const float4*)(qbase + ((i > 0) ? loff - WW : loff));
    const float  qlv = qbase[(jb > 0) ? loff - 1 : loff];
    const float4 o4  = *(const float4*)(o + goff);

    const float dx  = (float)(i + 1) - cxf;
    const float dxu = (float)i - cxf;
    const float qcv[4] = {qc4.x, qc4.y, qc4.z, qc4.w};
    const float quv[4] = {qu4.x, qu4.y, qu4.z, qu4.w};
    const float ov4[4] = {o4.x, o4.y, o4.z, o4.w};

    float a_c[4], b_c[4], qn[4], a_u[4];
    #pragma unroll
    for (int k = 0; k < 4; k++) {
        const float dy = (float)(jb + k + 1) - cyf;
        evalF(uc[k], ud[k], uc[k + 1], qcv[k],
              dx, dy, cossin, bsin, asin_, a_c[k], b_c[k], qn[k]);
        float au, bu_d, qu_d;
        evalF(uu[k], uc[k], uu[k + 1], quv[k],
              dxu, dy, cossin, bsin, asin_, au, bu_d, qu_d);
        a_u[k] = (i > 0) ? au : 0.f;
    }
    // left-neighbor b for element 0 (elements 1..3 reuse b_c[k-1])
    float b_l = 0.f;
    {
        float al_d, bl, ql_d;
        evalF(u2z.w, u3z.w, uc[0], qlv,
              dx, (float)jb - cyf, cossin, bsin, asin_, al_d, bl, ql_d);
        b_l = (jb > 0) ? bl : 0.f;
    }

    float un4[4], t4[4];
    #pragma unroll
    for (int k = 0; k < 4; k++) {
        const float bleft = (k == 0) ? b_l : b_c[k - 1];
        const float Tq = a_c[k] + b_c[k] - a_u[k] - bleft;
        t4[k]  = ov4[k] - p4[k] - Tq;
        un4[k] = sigmoidf(t4[k]);
    }

    *(float4*)(uB + goff) = make_float4(un4[0], un4[1], un4[2], un4[3]);
    *(float4*)(qB + goff) = make_float4(qn[0], qn[1], qn[2], qn[3]);
    if (lastFlag) *(float4*)(out + goff) = make_float4(t4[0], t4[1], t4[2], t4[3]);

    // ---- next-iteration sums ----
    const float x = (float)(i + 1);
    float s0 = 0.f, sy = 0.f, syy = 0.f;
    #pragma unroll
    for (int k = 0; k < 4; k++) {
        const float y = (float)(jb + k + 1);
        s0  += un4[k];
        sy  += un4[k] * y;
        syy += un4[k] * y * y;
    }
    float v[6] = {s0, x * s0, sy, x * sy, x * x * s0, syy};
    const int slot = (blockIdx.y * 8 + blockIdx.x) & (SLOTS - 1);
    reduce6_atomic(v, sumsOut + b * BATCH_STRIDE + slot * SLOT_STRIDE);
}

extern "C" void kernel_launch(void* const* d_in, const int* in_sizes, int n_in,
                              void* d_out, int out_size, void* d_ws, size_t ws_size,
                              hipStream_t stream) {
    const float* o = (const float*)d_in[0];
    float* out = (float*)d_out;

    float* ws = (float*)d_ws;
    float* uA = ws;
    float* uB = ws + (size_t)NTOT;
    float* qA = ws + 2 * (size_t)NTOT;
    float* qB = ws + 3 * (size_t)NTOT;
    double* sums = (double*)(ws + 4 * (size_t)NTOT);   // 51 iters * 1024 doubles

    hipMemsetAsync(sums, 0, (size_t)(ITER + 1) * ITER_STRIDE * sizeof(double), stream);
    init_kernel<<<2048, 256, 0, stream>>>(o, uA, qA, sums);

    float *ua = uA, *ub = uB, *qa = qA, *qb = qB;
    for (int k = 0; k < ITER; k++) {
        step_kernel<<<dim3(WW / TX, HH / TY, BB), 256, 0, stream>>>(
            o, ua, qa, ub, qb,
            sums + (size_t)k * ITER_STRIDE,
            sums + (size_t)(k + 1) * ITER_STRIDE,
            out, (k == ITER - 1) ? 1 : 0);
        float* tmp;
        tmp = ua; ua = ub; ub = tmp;
        tmp = qa; qa = qb; qb = tmp;
    }
}

// Round 5
// 946.516 us; speedup vs baseline: 14.5282x; 1.0488x over previous
//
#include <hip/hip_runtime.h>
#include <math.h>

#define HH 512
#define WW 512
#define BB 8
#define NPIX (HH*WW)        // 262144
#define NTOT (BB*NPIX)      // 2097152
#define ITER 50

#define TX 64
#define TY 16
#define SU_STRIDE 72        // floats; 288 B rows -> 16B aligned, quad-uniform for b128
#define SH_STRIDE 64        // floats; 256 B rows

// partials layout: per iteration: [8 batches][256 blocks][8 floats] (0..5 used)
#define BLK_PER_BATCH 256
#define PART_ITER_STRIDE (BB*BLK_PER_BATCH*8)   // 16384 floats per iteration

// Gaussian 5x5 (sigma=5): w1d(d) = exp(-d^2/50), d=-2..2, normalized by (sum)^2
constexpr double W0d = 0.92311634638663587;  // exp(-0.08)
constexpr double W1d = 0.98019867330675525;  // exp(-0.02)
constexpr double SUM1D = 1.0 + 2.0*(W0d + W1d);
constexpr float  INV_NORM = (float)(1.0/(SUM1D*SUM1D + 1e-15));
constexpr float  W0f = (float)W0d;
constexpr float  W1f = (float)W1d;
constexpr float  S1f = (float)SUM1D;

__device__ __forceinline__ float sigmoidf(float x) {
    return 1.0f / (1.0f + expf(-x));
}

// in-bounds 1D weight sum at coordinate v (0..511)
__device__ __forceinline__ float edge1d(int v) {
    float r = S1f;
    if (v == 0 || v == HH - 1) r = S1f - W0f - W1f;
    else if (v == 1 || v == HH - 2) r = S1f - W0f;
    return r;
}

// Block-level reduce of 6 floats (256 threads = 4 waves), then ONE plain store
// by thread 0 into this block's private partials slot (8 floats). No atomics.
__device__ __forceinline__ void reduce6_store(float v[6], float* dst8) {
    #pragma unroll
    for (int k = 0; k < 6; k++) {
        float x = v[k];
        #pragma unroll
        for (int off = 32; off > 0; off >>= 1) x += __shfl_down(x, off, 64);
        v[k] = x;
    }
    __shared__ float sm[4][6];
    const int lane = threadIdx.x & 63;
    const int wv   = threadIdx.x >> 6;
    if (lane == 0) {
        #pragma unroll
        for (int k = 0; k < 6; k++) sm[wv][k] = v[k];
    }
    __syncthreads();
    if (threadIdx.x == 0) {
        float t[6];
        #pragma unroll
        for (int k = 0; k < 6; k++) t[k] = sm[0][k] + sm[1][k] + sm[2][k] + sm[3][k];
        *(float4*)dst8       = make_float4(t[0], t[1], t[2], t[3]);
        *(float4*)(dst8 + 4) = make_float4(t[4], t[5], 0.f, 0.f);
    }
}

// orientation-field pointwise eval
__device__ __forceinline__ void evalF(float uc, float ud, float ur, float qv,
                                      float dx, float dy,
                                      float cossin, float bsin, float asin_,
                                      float& a, float& bv, float& qn) {
    float Tx = -dx * cossin + dy * bsin;
    float Ty =  dy * cossin - dx * asin_;
    const float rn = 1.0f / (sqrtf(Tx * Tx + Ty * Ty) + 1e-10f);
    Tx *= rn; Ty *= rn;
    qn = qv - ((ud - uc) * Tx + (ur - uc) * Ty);
    a  = Tx * qn;
    bv = Ty * qn;
}

// u0 = sigmoid(o); q0 = 0; write partials[0]  (4 pixels/thread, 2048 blocks)
__global__ __launch_bounds__(256) void init_kernel(const float* __restrict__ o,
                                                   float* __restrict__ u,
                                                   float* __restrict__ q,
                                                   float* __restrict__ part0) {
    const int t   = blockIdx.x * 256 + threadIdx.x;
    const int pix = t * 4;
    const int bb  = blockIdx.x >> 8;          // 256 blocks per batch
    const int blkInBatch = blockIdx.x & 255;
    const int within = pix & (NPIX - 1);
    const int i = within >> 9;
    const int j = within & (WW - 1);

    float4 ov = *(const float4*)(o + pix);
    float4 uv;
    uv.x = sigmoidf(ov.x);
    uv.y = sigmoidf(ov.y);
    uv.z = sigmoidf(ov.z);
    uv.w = sigmoidf(ov.w);
    *(float4*)(u + pix) = uv;
    *(float4*)(q + pix) = make_float4(0.f, 0.f, 0.f, 0.f);

    const float x = (float)(i + 1);
    float v[6] = {0.f, 0.f, 0.f, 0.f, 0.f, 0.f};
    float us[4] = {uv.x, uv.y, uv.z, uv.w};
    #pragma unroll
    for (int kk = 0; kk < 4; kk++) {
        float uu = us[kk];
        float y  = (float)(j + 1 + kk);
        v[0] += uu;
        v[1] += uu * x;
        v[2] += uu * y;
        v[3] += uu * x * y;
        v[4] += uu * x * x;
        v[5] += uu * y * y;
    }
    reduce6_store(v, part0 + ((size_t)bb * BLK_PER_BATCH + blkInBatch) * 8);
}

// One fused iteration, all-vectorized LDS, atomic-free reduction.
// su tile col t <-> image col j0 + t - 4 (t=2..69 valid; rows: r <-> i0 + r - 2)
__global__ __launch_bounds__(256) void step_kernel(const float* __restrict__ o,
                                                   const float* __restrict__ uA,
                                                   const float* __restrict__ qA,
                                                   float* __restrict__ uB,
                                                   float* __restrict__ qB,
                                                   const float* __restrict__ partIn,
                                                   float* __restrict__ partOut,
                                                   float* __restrict__ out,
                                                   int lastFlag) {
    const int j0 = blockIdx.x * TX;
    const int i0 = blockIdx.y * TY;
    const int b  = blockIdx.z;
    const int blkInBatch = blockIdx.x + 8 * blockIdx.y;   // 0..255
    const float* ubase = uA + (size_t)b * NPIX;
    const float* qbase = qA + (size_t)b * NPIX;

    __shared__ __align__(16) float su[TY + 4][SU_STRIDE];
    __shared__ __align__(16) float sh[TY + 4][SH_STRIDE];
    __shared__ float smF[4][6];            // finalize wave partials
    __shared__ float sc[5];                // cx, cy, cossin, bsin, asin

    const int lin = threadIdx.x;

    // ---- finalize input: each thread reads one block-partial of this batch ----
    const float* Pin = partIn + (size_t)b * BLK_PER_BATCH * 8 + lin * 8;
    const float4 pa = *(const float4*)Pin;
    const float4 pb = *(const float4*)(Pin + 4);

    // ---- stage u tile: main body as float4 (20 rows x 16 groups) ----
    #pragma unroll
    for (int e = lin; e < (TY + 4) * 16; e += 256) {
        const int r = e >> 4, g = e & 15;
        const int ii = i0 + r - 2;
        float4 v = make_float4(0.f, 0.f, 0.f, 0.f);
        if (ii >= 0 && ii < HH)
            v = *(const float4*)(ubase + ii * WW + j0 + 4 * g);
        *(float4*)&su[r][4 * g + 4] = v;
    }
    // halo columns: t=2,3 (img j0-2,j0-1) and t=68,69 (img j0+64,j0+65); zero OOB
    if (lin < TY + 4) {
        const int r = lin;
        const int ii = i0 + r - 2;
        float2 lv = make_float2(0.f, 0.f);
        float2 rv = make_float2(0.f, 0.f);
        if (ii >= 0 && ii < HH) {
            if (j0 > 0)       lv = *(const float2*)(ubase + ii * WW + j0 - 2);
            if (j0 + TX < WW) rv = *(const float2*)(ubase + ii * WW + j0 + TX);
        }
        *(float2*)&su[r][2]  = lv;
        *(float2*)&su[r][68] = rv;
    }

    // ---- finalize: wave-tree reduce the 256 partials (6 counters) ----
    {
        float v[6] = {pa.x, pa.y, pa.z, pa.w, pb.x, pb.y};
        #pragma unroll
        for (int off = 32; off > 0; off >>= 1) {
            #pragma unroll
            for (int c = 0; c < 6; c++) v[c] += __shfl_down(v[c], off, 64);
        }
        if ((lin & 63) == 0) {
            #pragma unroll
            for (int c = 0; c < 6; c++) smF[lin >> 6][c] = v[c];
        }
    }
    __syncthreads();

    if (lin == 0) {
        double v[6];
        #pragma unroll
        for (int c = 0; c < 6; c++)
            v[c] = (double)smF[0][c] + (double)smF[1][c]
                 + (double)smF[2][c] + (double)smF[3][c];
        const double s   = v[0];
        const double inv = 1.0 / s;
        const double cx  = v[1] * inv;
        const double cy  = v[2] * inv;
        sc[0] = (float)cx;
        sc[1] = (float)cy;
        sc[2] = (float)(v[3] * inv - cx * cy);
        sc[3] = (float)(v[4] * inv - cx * cx);
        sc[4] = (float)(v[5] * inv - cy * cy);
    }

    // ---- horizontal gaussian pass: 4 outputs per task from 3 float4 reads ----
    #pragma unroll
    for (int e = lin; e < (TY + 4) * 16; e += 256) {
        const int r = e >> 4, g = e & 15;
        const int c0 = 4 * g;
        const float4 A  = *(const float4*)&su[r][c0];
        const float4 Bv = *(const float4*)&su[r][c0 + 4];
        const float4 Cv = *(const float4*)&su[r][c0 + 8];
        const float v0 = A.z,  v1 = A.w,  v2 = Bv.x, v3 = Bv.y;
        const float v4 = Bv.z, v5 = Bv.w, v6 = Cv.x, v7 = Cv.y;
        float4 hres;
        hres.x = W0f * v0 + W1f * v1 + v2 + W1f * v3 + W0f * v4;
        hres.y = W0f * v1 + W1f * v2 + v3 + W1f * v4 + W0f * v5;
        hres.z = W0f * v2 + W1f * v3 + v4 + W1f * v5 + W0f * v6;
        hres.w = W0f * v3 + W1f * v4 + v5 + W1f * v6 + W0f * v7;
        *(float4*)&sh[r][c0] = hres;
    }
    __syncthreads();

    const float cxf    = sc[0];
    const float cyf    = sc[1];
    const float cossin = sc[2];
    const float bsin   = sc[3];
    const float asin_  = sc[4];

    const int tx = lin & 15;
    const int ty = lin >> 4;
    const int i  = i0 + ty;
    const int jb = j0 + 4 * tx;
    const int loff = i * WW + jb;
    const size_t goff = (size_t)b * NPIX + loff;

    // ---- vertical gaussian pass (5 float4 reads) + analytic zero-pad fix ----
    float p4[4];
    {
        const float4 r0 = *(const float4*)&sh[ty][4 * tx];
        const float4 r1 = *(const float4*)&sh[ty + 1][4 * tx];
        const float4 r2 = *(const float4*)&sh[ty + 2][4 * tx];
        const float4 r3 = *(const float4*)&sh[ty + 3][4 * tx];
        const float4 r4 = *(const float4*)&sh[ty + 4][4 * tx];
        const float cU0 = W0f * r0.x + W1f * r1.x + r2.x + W1f * r3.x + W0f * r4.x;
        const float cU1 = W0f * r0.y + W1f * r1.y + r2.y + W1f * r3.y + W0f * r4.y;
        const float cU2 = W0f * r0.z + W1f * r1.z + r2.z + W1f * r3.z + W0f * r4.z;
        const float cU3 = W0f * r0.w + W1f * r1.w + r2.w + W1f * r3.w + W0f * r4.w;
        const float Ri = edge1d(i);
        p4[0] = INV_NORM * (Ri * edge1d(jb)     - 2.0f * cU0);
        p4[1] = INV_NORM * (Ri * edge1d(jb + 1) - 2.0f * cU1);
        p4[2] = INV_NORM * (Ri * edge1d(jb + 2) - 2.0f * cU2);
        p4[3] = INV_NORM * (Ri * edge1d(jb + 3) - 2.0f * cU3);
    }

    // ---- u fragments (aligned float4; quad-uniform -> conflict-free) ----
    const float4 u1a = *(const float4*)&su[ty + 1][4 * tx + 4];
    const float4 u1b = *(const float4*)&su[ty + 1][4 * tx + 8];
    const float4 u2z = *(const float4*)&su[ty + 2][4 * tx];
    const float4 u2a = *(const float4*)&su[ty + 2][4 * tx + 4];
    const float4 u2b = *(const float4*)&su[ty + 2][4 * tx + 8];
    const float4 u3z = *(const float4*)&su[ty + 3][4 * tx];
    const float4 u3a = *(const float4*)&su[ty + 3][4 * tx + 4];

    const float uc[5] = {u2a.x, u2a.y, u2a.z, u2a.w, u2b.x};   // row i
    const float ud[4] = {u3a.x, u3a.y, u3a.z, u3a.w};          // row i+1
    const float uu[5] = {u1a.x, u1a.y, u1a.z, u1a.w, u1b.x};   // row i-1

    // ---- q / o loads (clamped addresses, branchless select) ----
    const float4 qc4 = *(const float4*)(qbase + loff);
    const float4 qu4 = *(const float4*)(qbase + ((i > 0) ? loff - WW : loff));
    const float  qlv = qbase[(jb > 0) ? loff - 1 : loff];
    const float4 o4  = *(const float4*)(o + goff);

    const float dx  = (float)(i + 1) - cxf;
    const float dxu = (float)i - cxf;
    const float qcv[4] = {qc4.x, qc4.y, qc4.z, qc4.w};
    const float quv[4] = {qu4.x, qu4.y, qu4.z, qu4.w};
    const float ov4[4] = {o4.x, o4.y, o4.z, o4.w};

    float a_c[4], b_c[4], qn[4], a_u[4];
    #pragma unroll
    for (int k = 0; k < 4; k++) {
        const float dy = (float)(jb + k + 1) - cyf;
        evalF(uc[k], ud[k], uc[k + 1], qcv[k],
              dx, dy, cossin, bsin, asin_, a_c[k], b_c[k], qn[k]);
        float au, bu_d, qu_d;
        evalF(uu[k], uc[k], uu[k + 1], quv[k],
              dxu, dy, cossin, bsin, asin_, au, bu_d, qu_d);
        a_u[k] = (i > 0) ? au : 0.f;
    }
    // left-neighbor b for element 0 (elements 1..3 reuse b_c[k-1])
    float b_l = 0.f;
    {
        float al_d, bl, ql_d;
        evalF(u2z.w, u3z.w, uc[0], qlv,
              dx, (float)jb - cyf, cossin, bsin, asin_, al_d, bl, ql_d);
        b_l = (jb > 0) ? bl : 0.f;
    }

    float un4[4], t4[4];
    #pragma unroll
    for (int k = 0; k < 4; k++) {
        const float bleft = (k == 0) ? b_l : b_c[k - 1];
        const float Tq = a_c[k] + b_c[k] - a_u[k] - bleft;
        t4[k]  = ov4[k] - p4[k] - Tq;
        un4[k] = sigmoidf(t4[k]);
    }

    *(float4*)(uB + goff) = make_float4(un4[0], un4[1], un4[2], un4[3]);
    *(float4*)(qB + goff) = make_float4(qn[0], qn[1], qn[2], qn[3]);
    if (lastFlag) *(float4*)(out + goff) = make_float4(t4[0], t4[1], t4[2], t4[3]);

    // ---- next-iteration partial sums (atomic-free) ----
    const float x = (float)(i + 1);
    float s0 = 0.f, sy = 0.f, syy = 0.f;
    #pragma unroll
    for (int k = 0; k < 4; k++) {
        const float y = (float)(jb + k + 1);
        s0  += un4[k];
        sy  += un4[k] * y;
        syy += un4[k] * y * y;
    }
    float v[6] = {s0, x * s0, sy, x * sy, x * x * s0, syy};
    reduce6_store(v, partOut + ((size_t)b * BLK_PER_BATCH + blkInBatch) * 8);
}

extern "C" void kernel_launch(void* const* d_in, const int* in_sizes, int n_in,
                              void* d_out, int out_size, void* d_ws, size_t ws_size,
                              hipStream_t stream) {
    const float* o = (const float*)d_in[0];
    float* out = (float*)d_out;

    float* ws = (float*)d_ws;
    float* uA = ws;
    float* uB = ws + (size_t)NTOT;
    float* qA = ws + 2 * (size_t)NTOT;
    float* qB = ws + 3 * (size_t)NTOT;
    float* partials = ws + 4 * (size_t)NTOT;   // 51 iters * 16384 floats = 3.3 MB

    init_kernel<<<2048, 256, 0, stream>>>(o, uA, qA, partials);

    float *ua = uA, *ub = uB, *qa = qA, *qb = qB;
    for (int k = 0; k < ITER; k++) {
        step_kernel<<<dim3(WW / TX, HH / TY, BB), 256, 0, stream>>>(
            o, ua, qa, ub, qb,
            partials + (size_t)k * PART_ITER_STRIDE,
            partials + (size_t)(k + 1) * PART_ITER_STRIDE,
            out, (k == ITER - 1) ? 1 : 0);
        float* tmp;
        tmp = ua; ua = ub; ub = tmp;
        tmp = qa; qa = qb; qb = tmp;
    }
}

// Round 6
// 940.638 us; speedup vs baseline: 14.6189x; 1.0062x over previous
//
#include <hip/hip_runtime.h>
#include <math.h>

#define HH 512
#define WW 512
#define BB 8
#define NPIX (HH*WW)        // 262144
#define NTOT (BB*NPIX)      // 2097152
#define ITER 50

#define TX 64
#define TY 16
#define SU_STRIDE 72        // floats; 288 B rows -> 16B aligned, quad-uniform for b128
#define SH_STRIDE 64        // floats; 256 B rows

// partials layout: per iteration: [8 batches][256 blocks][8 floats] (0..5 used)
#define BLK_PER_BATCH 256
#define PART_ITER_STRIDE (BB*BLK_PER_BATCH*8)   // 16384 floats per iteration

// Gaussian 5x5 (sigma=5): w1d(d) = exp(-d^2/50), d=-2..2, normalized by (sum)^2
constexpr double W0d = 0.92311634638663587;  // exp(-0.08)
constexpr double W1d = 0.98019867330675525;  // exp(-0.02)
constexpr double SUM1D = 1.0 + 2.0*(W0d + W1d);
constexpr float  INV_NORM = (float)(1.0/(SUM1D*SUM1D + 1e-15));
constexpr float  W0f = (float)W0d;
constexpr float  W1f = (float)W1d;
constexpr float  S1f = (float)SUM1D;

__device__ __forceinline__ float sigmoidf(float x) {
    return 1.0f / (1.0f + expf(-x));
}

// in-bounds 1D weight sum at coordinate v (0..511)
__device__ __forceinline__ float edge1d(int v) {
    float r = S1f;
    if (v == 0 || v == HH - 1) r = S1f - W0f - W1f;
    else if (v == 1 || v == HH - 2) r = S1f - W0f;
    return r;
}

// Block-level reduce of 6 floats (256 threads = 4 waves), then ONE plain store
// by thread 0 into this block's private partials slot (8 floats). No atomics.
__device__ __forceinline__ void reduce6_store(float v[6], float* dst8) {
    #pragma unroll
    for (int k = 0; k < 6; k++) {
        float x = v[k];
        #pragma unroll
        for (int off = 32; off > 0; off >>= 1) x += __shfl_down(x, off, 64);
        v[k] = x;
    }
    __shared__ float sm[4][6];
    const int lane = threadIdx.x & 63;
    const int wv   = threadIdx.x >> 6;
    if (lane == 0) {
        #pragma unroll
        for (int k = 0; k < 6; k++) sm[wv][k] = v[k];
    }
    __syncthreads();
    if (threadIdx.x == 0) {
        float t[6];
        #pragma unroll
        for (int k = 0; k < 6; k++) t[k] = sm[0][k] + sm[1][k] + sm[2][k] + sm[3][k];
        *(float4*)dst8       = make_float4(t[0], t[1], t[2], t[3]);
        *(float4*)(dst8 + 4) = make_float4(t[4], t[5], 0.f, 0.f);
    }
}

// orientation-field pointwise eval
__device__ __forceinline__ void evalF(float uc, float ud, float ur, float qv,
                                      float dx, float dy,
                                      float cossin, float bsin, float asin_,
                                      float& a, float& bv, float& qn) {
    float Tx = -dx * cossin + dy * bsin;
    float Ty =  dy * cossin - dx * asin_;
    const float rn = 1.0f / (sqrtf(Tx * Tx + Ty * Ty) + 1e-10f);
    Tx *= rn; Ty *= rn;
    qn = qv - ((ud - uc) * Tx + (ur - uc) * Ty);
    a  = Tx * qn;
    bv = Ty * qn;
}

// u0 = sigmoid(o); q0 = 0; write partials[0]
// XCD swizzle: batch = blockIdx.x & 7 (8 XCDs round-robin on flat id) so each
// XCD's L2 only ever sees one batch's buffers.
__global__ __launch_bounds__(256) void init_kernel(const float* __restrict__ o,
                                                   float* __restrict__ u,
                                                   float* __restrict__ q,
                                                   float* __restrict__ part0) {
    const int b     = blockIdx.x & 7;
    const int chunk = blockIdx.x >> 3;        // 0..255, 1024 px each
    const int within = chunk * 1024 + threadIdx.x * 4;
    const int pix = b * NPIX + within;
    const int i = within >> 9;
    const int j = within & (WW - 1);

    float4 ov = *(const float4*)(o + pix);
    float4 uv;
    uv.x = sigmoidf(ov.x);
    uv.y = sigmoidf(ov.y);
    uv.z = sigmoidf(ov.z);
    uv.w = sigmoidf(ov.w);
    *(float4*)(u + pix) = uv;
    *(float4*)(q + pix) = make_float4(0.f, 0.f, 0.f, 0.f);

    const float x = (float)(i + 1);
    float v[6] = {0.f, 0.f, 0.f, 0.f, 0.f, 0.f};
    float us[4] = {uv.x, uv.y, uv.z, uv.w};
    #pragma unroll
    for (int kk = 0; kk < 4; kk++) {
        float uu = us[kk];
        float y  = (float)(j + 1 + kk);
        v[0] += uu;
        v[1] += uu * x;
        v[2] += uu * y;
        v[3] += uu * x * y;
        v[4] += uu * x * x;
        v[5] += uu * y * y;
    }
    reduce6_store(v, part0 + ((size_t)b * BLK_PER_BATCH + chunk) * 8);
}

// One fused iteration, all-vectorized LDS, atomic-free reduction, XCD-pinned.
// 1D grid of 2048 blocks: batch = blk & 7, tile = blk >> 3 (256 tiles: 8 in x, 32 in y).
__global__ __launch_bounds__(256) void step_kernel(const float* __restrict__ o,
                                                   const float* __restrict__ uA,
                                                   const float* __restrict__ qA,
                                                   float* __restrict__ uB,
                                                   float* __restrict__ qB,
                                                   const float* __restrict__ partIn,
                                                   float* __restrict__ partOut,
                                                   float* __restrict__ out,
                                                   int lastFlag) {
    const int b    = blockIdx.x & 7;
    const int tile = blockIdx.x >> 3;          // 0..255
    const int j0 = (tile & 7) * TX;
    const int i0 = (tile >> 3) * TY;
    const int blkInBatch = tile;
    const float* ubase = uA + (size_t)b * NPIX;
    const float* qbase = qA + (size_t)b * NPIX;

    __shared__ __align__(16) float su[TY + 4][SU_STRIDE];
    __shared__ __align__(16) float sh[TY + 4][SH_STRIDE];
    __shared__ float smF[4][6];            // finalize wave partials
    __shared__ float sc[5];                // cx, cy, cossin, bsin, asin

    const int lin = threadIdx.x;

    // ---- finalize input: each thread reads one block-partial of this batch ----
    const float* Pin = partIn + (size_t)b * BLK_PER_BATCH * 8 + lin * 8;
    const float4 pa = *(const float4*)Pin;
    const float4 pb = *(const float4*)(Pin + 4);

    // ---- stage u tile: main body as float4 (20 rows x 16 groups) ----
    #pragma unroll
    for (int e = lin; e < (TY + 4) * 16; e += 256) {
        const int r = e >> 4, g = e & 15;
        const int ii = i0 + r - 2;
        float4 v = make_float4(0.f, 0.f, 0.f, 0.f);
        if (ii >= 0 && ii < HH)
            v = *(const float4*)(ubase + ii * WW + j0 + 4 * g);
        *(float4*)&su[r][4 * g + 4] = v;
    }
    // halo columns: t=2,3 (img j0-2,j0-1) and t=68,69 (img j0+64,j0+65); zero OOB
    if (lin < TY + 4) {
        const int r = lin;
        const int ii = i0 + r - 2;
        float2 lv = make_float2(0.f, 0.f);
        float2 rv = make_float2(0.f, 0.f);
        if (ii >= 0 && ii < HH) {
            if (j0 > 0)       lv = *(const float2*)(ubase + ii * WW + j0 - 2);
            if (j0 + TX < WW) rv = *(const float2*)(ubase + ii * WW + j0 + TX);
        }
        *(float2*)&su[r][2]  = lv;
        *(float2*)&su[r][68] = rv;
    }

    // ---- finalize: wave-tree reduce the 256 partials (6 counters) ----
    {
        float v[6] = {pa.x, pa.y, pa.z, pa.w, pb.x, pb.y};
        #pragma unroll
        for (int off = 32; off > 0; off >>= 1) {
            #pragma unroll
            for (int c = 0; c < 6; c++) v[c] += __shfl_down(v[c], off, 64);
        }
        if ((lin & 63) == 0) {
            #pragma unroll
            for (int c = 0; c < 6; c++) smF[lin >> 6][c] = v[c];
        }
    }
    __syncthreads();

    if (lin == 0) {
        double v[6];
        #pragma unroll
        for (int c = 0; c < 6; c++)
            v[c] = (double)smF[0][c] + (double)smF[1][c]
                 + (double)smF[2][c] + (double)smF[3][c];
        const double s   = v[0];
        const double inv = 1.0 / s;
        const double cx  = v[1] * inv;
        const double cy  = v[2] * inv;
        sc[0] = (float)cx;
        sc[1] = (float)cy;
        sc[2] = (float)(v[3] * inv - cx * cy);
        sc[3] = (float)(v[4] * inv - cx * cx);
        sc[4] = (float)(v[5] * inv - cy * cy);
    }

    // ---- horizontal gaussian pass: 4 outputs per task from 3 float4 reads ----
    #pragma unroll
    for (int e = lin; e < (TY + 4) * 16; e += 256) {
        const int r = e >> 4, g = e & 15;
        const int c0 = 4 * g;
        const float4 A  = *(const float4*)&su[r][c0];
        const float4 Bv = *(const float4*)&su[r][c0 + 4];
        const float4 Cv = *(const float4*)&su[r][c0 + 8];
        const float v0 = A.z,  v1 = A.w,  v2 = Bv.x, v3 = Bv.y;
        const float v4 = Bv.z, v5 = Bv.w, v6 = Cv.x, v7 = Cv.y;
        float4 hres;
        hres.x = W0f * v0 + W1f * v1 + v2 + W1f * v3 + W0f * v4;
        hres.y = W0f * v1 + W1f * v2 + v3 + W1f * v4 + W0f * v5;
        hres.z = W0f * v2 + W1f * v3 + v4 + W1f * v5 + W0f * v6;
        hres.w = W0f * v3 + W1f * v4 + v5 + W1f * v6 + W0f * v7;
        *(float4*)&sh[r][c0] = hres;
    }
    __syncthreads();

    const float cxf    = sc[0];
    const float cyf    = sc[1];
    const float cossin = sc[2];
    const float bsin   = sc[3];
    const float asin_  = sc[4];

    const int tx = lin & 15;
    const int ty = lin >> 4;
    const int i  = i0 + ty;
    const int jb = j0 + 4 * tx;
    const int loff = i * WW + jb;
    const size_t goff = (size_t)b * NPIX + loff;

    // ---- vertical gaussian pass (5 float4 reads) + analytic zero-pad fix ----
    float p4[4];
    {
        const float4 r0 = *(const float4*)&sh[ty][4 * tx];
        const float4 r1 = *(const float4*)&sh[ty + 1][4 * tx];
        const float4 r2 = *(const float4*)&sh[ty + 2][4 * tx];
        const float4 r3 = *(const float4*)&sh[ty + 3][4 * tx];
        const float4 r4 = *(const float4*)&sh[ty + 4][4 * tx];
        const float cU0 = W0f * r0.x + W1f * r1.x + r2.x + W1f * r3.x + W0f * r4.x;
        const float cU1 = W0f * r0.y + W1f * r1.y + r2.y + W1f * r3.y + W0f * r4.y;
        const float cU2 = W0f * r0.z + W1f * r1.z + r2.z + W1f * r3.z + W0f * r4.z;
        const float cU3 = W0f * r0.w + W1f * r1.w + r2.w + W1f * r3.w + W0f * r4.w;
        const float Ri = edge1d(i);
        p4[0] = INV_NORM * (Ri * edge1d(jb)     - 2.0f * cU0);
        p4[1] = INV_NORM * (Ri * edge1d(jb + 1) - 2.0f * cU1);
        p4[2] = INV_NORM * (Ri * edge1d(jb + 2) - 2.0f * cU2);
        p4[3] = INV_NORM * (Ri * edge1d(jb + 3) - 2.0f * cU3);
    }

    // ---- u fragments (aligned float4; quad-uniform -> conflict-free) ----
    const float4 u1a = *(const float4*)&su[ty + 1][4 * tx + 4];
    const float4 u1b = *(const float4*)&su[ty + 1][4 * tx + 8];
    const float4 u2z = *(const float4*)&su[ty + 2][4 * tx];
    const float4 u2a = *(const float4*)&su[ty + 2][4 * tx + 4];
    const float4 u2b = *(const float4*)&su[ty + 2][4 * tx + 8];
    const float4 u3z = *(const float4*)&su[ty + 3][4 * tx];
    const float4 u3a = *(const float4*)&su[ty + 3][4 * tx + 4];

    const float uc[5] = {u2a.x, u2a.y, u2a.z, u2a.w, u2b.x};   // row i
    const float ud[4] = {u3a.x, u3a.y, u3a.z, u3a.w};          // row i+1
    const float uu[5] = {u1a.x, u1a.y, u1a.z, u1a.w, u1b.x};   // row i-1

    // ---- q / o loads (clamped addresses, branchless select) ----
    const float4 qc4 = *(const float4*)(qbase + loff);
    const float4 qu4 = *(const float4*)(qbase + ((i > 0) ? loff - WW : loff));
    const float  qlv = qbase[(jb > 0) ? loff - 1 : loff];
    const float4 o4  = *(const float4*)(o + goff);

    const float dx  = (float)(i + 1) - cxf;
    const float dxu = (float)i - cxf;
    const float qcv[4] = {qc4.x, qc4.y, qc4.z, qc4.w};
    const float quv[4] = {qu4.x, qu4.y, qu4.z, qu4.w};
    const float ov4[4] = {o4.x, o4.y, o4.z, o4.w};

    float a_c[4], b_c[4], qn[4], a_u[4];
    #pragma unroll
    for (int k = 0; k < 4; k++) {
        const float dy = (float)(jb + k + 1) - cyf;
        evalF(uc[k], ud[k], uc[k + 1], qcv[k],
              dx, dy, cossin, bsin, asin_, a_c[k], b_c[k], qn[k]);
        float au, bu_d, qu_d;
        evalF(uu[k], uc[k], uu[k + 1], quv[k],
              dxu, dy, cossin, bsin, asin_, au, bu_d, qu_d);
        a_u[k] = (i > 0) ? au : 0.f;
    }
    // left-neighbor b for element 0 (elements 1..3 reuse b_c[k-1])
    float b_l = 0.f;
    {
        float al_d, bl, ql_d;
        evalF(u2z.w, u3z.w, uc[0], qlv,
              dx, (float)jb - cyf, cossin, bsin, asin_, al_d, bl, ql_d);
        b_l = (jb > 0) ? bl : 0.f;
    }

    float un4[4], t4[4];
    #pragma unroll
    for (int k = 0; k < 4; k++) {
        const float bleft = (k == 0) ? b_l : b_c[k - 1];
        const float Tq = a_c[k] + b_c[k] - a_u[k] - bleft;
        t4[k]  = ov4[k] - p4[k] - Tq;
        un4[k] = sigmoidf(t4[k]);
    }

    *(float4*)(uB + goff) = make_float4(un4[0], un4[1], un4[2], un4[3]);
    *(float4*)(qB + goff) = make_float4(qn[0], qn[1], qn[2], qn[3]);
    if (lastFlag) *(float4*)(out + goff) = make_float4(t4[0], t4[1], t4[2], t4[3]);

    // ---- next-iteration partial sums (atomic-free) ----
    const float x = (float)(i + 1);
    float s0 = 0.f, sy = 0.f, syy = 0.f;
    #pragma unroll
    for (int k = 0; k < 4; k++) {
        const float y = (float)(jb + k + 1);
        s0  += un4[k];
        sy  += un4[k] * y;
        syy += un4[k] * y * y;
    }
    float v[6] = {s0, x * s0, sy, x * sy, x * x * s0, syy};
    reduce6_store(v, partOut + ((size_t)b * BLK_PER_BATCH + blkInBatch) * 8);
}

extern "C" void kernel_launch(void* const* d_in, const int* in_sizes, int n_in,
                              void* d_out, int out_size, void* d_ws, size_t ws_size,
                              hipStream_t stream) {
    const float* o = (const float*)d_in[0];
    float* out = (float*)d_out;

    float* ws = (float*)d_ws;
    float* uA = ws;
    float* uB = ws + (size_t)NTOT;
    float* qA = ws + 2 * (size_t)NTOT;
    float* qB = ws + 3 * (size_t)NTOT;
    float* partials = ws + 4 * (size_t)NTOT;   // 51 iters * 16384 floats = 3.3 MB

    init_kernel<<<2048, 256, 0, stream>>>(o, uA, qA, partials);

    float *ua = uA, *ub = uB, *qa = qA, *qb = qB;
    for (int k = 0; k < ITER; k++) {
        step_kernel<<<2048, 256, 0, stream>>>(
            o, ua, qa, ub, qb,
            partials + (size_t)k * PART_ITER_STRIDE,
            partials + (size_t)(k + 1) * PART_ITER_STRIDE,
            out, (k == ITER - 1) ? 1 : 0);
        float* tmp;
        tmp = ua; ua = ub; ub = tmp;
        tmp = qa; qa = qb; qb = tmp;
    }
}